// Round 6
// baseline (457.919 us; speedup 1.0000x reference)
//
#include <hip/hip_runtime.h>
#include <math.h>

// x: (8, 4096, 2048) fp32, L=25. Morphological closing along H.
#define BB 8
#define HH 4096
#define WW 2048
#define FL 25              // filter length (fast path)
#define NB 16              // van Herk output blocks per tile
#define TH (NB * FL)       // 400 output rows per tile
#define WB 512             // columns per block = 256 threads x float2

static __device__ __forceinline__ float2 f2max(float2 a, float2 b) {
    return make_float2(fmaxf(a.x, b.x), fmaxf(a.y, b.y));
}
static __device__ __forceinline__ float2 f2min(float2 a, float2 b) {
    return make_float2(fminf(a.x, b.x), fminf(a.y, b.y));
}

// Register-only van Herk closing, 2 columns per thread (float2):
// wave = 512B contiguous per row-load, block = 2KiB; 50 independent loads
// in flight per thread per chunk. No LDS, no barriers.
__global__ __launch_bounds__(256, 2)
void mmv_kernel(const float* __restrict__ x, const int* __restrict__ pL,
                float* __restrict__ out)
{
    const int Lr = pL[0];

    if (Lr == FL) {
        const int tid = threadIdx.x;
        const int col = blockIdx.x * WB + 2 * tid;
        const int b   = blockIdx.z;
        const int h0  = blockIdx.y * TH;
        const size_t plane = (size_t)HH * WW;
        const float2* xc = reinterpret_cast<const float2*>(x + (size_t)b * plane + col);
        float2*       oc = reinterpret_cast<float2*>(out + (size_t)b * plane + col);
        const int RS = WW / 2;   // row stride in float2

        float2 Sprev[FL];   // carried suffix-max of current chunk
        float2 SminP[FL];   // carried suffix-min of previous mx-block
        float2 c[FL];       // current input chunk
        float2 m[FL];       // emitted mx-block

        for (int t = 0; t < NB + 2; ++t) {
            const int kbase = h0 + t * FL;

            // load chunk (clamped row -> edge padding); 25 independent float2 loads
            #pragma unroll
            for (int j = 0; j < FL; ++j) {
                int r = kbase + j - (FL - 1);
                r = r < 0 ? 0 : (r >= HH ? HH - 1 : r);
                c[j] = xc[(size_t)r * RS];
            }

            if (t >= 1) {
                // emit mx block t-1: m[j] = max(Sprev[j], prefix(c)[j-1])
                float2 run = c[0];
                m[0] = Sprev[0];
                #pragma unroll
                for (int j = 1; j < FL; ++j) {
                    m[j] = f2max(Sprev[j], run);
                    run  = f2max(run, c[j]);
                }
            }
            // suffix-max of c -> Sprev
            Sprev[FL - 1] = c[FL - 1];
            #pragma unroll
            for (int j = FL - 2; j >= 0; --j) Sprev[j] = f2max(c[j], Sprev[j + 1]);

            if (t >= 2) {
                // emit mn block t-2: min-combine(SminP, prefix-min(m)), store direct
                const int row = h0 + (t - 2) * FL;
                float2 run2 = m[0];
                if (row < HH) oc[(size_t)row * RS] = SminP[0];
                #pragma unroll
                for (int j = 1; j < FL; ++j) {
                    float2 o = f2min(SminP[j], run2);
                    run2     = f2min(run2, m[j]);
                    if (row + j < HH) oc[(size_t)(row + j) * RS] = o;
                }
            }
            if (t >= 1) {
                // suffix-min of m -> SminP
                SminP[FL - 1] = m[FL - 1];
                #pragma unroll
                for (int j = FL - 2; j >= 0; --j) SminP[j] = f2min(m[j], SminP[j + 1]);
            }
        }
    } else {
        // ---------------- generic fallback (never hit in bench) ----------------
        const size_t total    = (size_t)BB * HH * WW;
        const size_t nthreads = (size_t)gridDim.x * gridDim.y * gridDim.z * blockDim.x;
        const size_t bid = blockIdx.x + (size_t)gridDim.x * (blockIdx.y + (size_t)gridDim.y * blockIdx.z);
        size_t tid = bid * blockDim.x + threadIdx.x;

        if (Lr == 1) {
            for (size_t e = tid; e < total; e += nthreads) {
                int w = (int)(e % WW);
                size_t t2 = e / WW;
                int h = (int)(t2 % HH);
                int b = (int)(t2 / HH);
                int hs = (h + 1 < HH) ? h + 1 : HH - 1;
                out[e] = x[((size_t)b * HH + hs) * WW + w];
            }
        } else {
            for (size_t e = tid; e < total; e += nthreads) {
                int w = (int)(e % WW);
                size_t t2 = e / WW;
                int h = (int)(t2 % HH);
                int b = (int)(t2 / HH);
                const float* xc = x + (size_t)b * HH * WW + w;
                float mn = INFINITY;
                for (int i = h; i < h + Lr; ++i) {
                    float mx = -INFINITY;
                    for (int k = i; k < i + Lr; ++k) {
                        int r = k - (Lr - 1);
                        r = r < 0 ? 0 : (r >= HH ? HH - 1 : r);
                        mx = fmaxf(mx, xc[(size_t)r * WW]);
                    }
                    mn = fminf(mn, mx);
                }
                out[e] = mn;
            }
        }
    }
}

extern "C" void kernel_launch(void* const* d_in, const int* in_sizes, int n_in,
                              void* d_out, int out_size, void* d_ws, size_t ws_size,
                              hipStream_t stream) {
    const float* x  = (const float*)d_in[0];
    const int*   pL = (const int*)d_in[1];
    float*       o  = (float*)d_out;

    dim3 block(256, 1, 1);
    dim3 grid(WW / WB, (HH + TH - 1) / TH, BB);   // 4 x 11 x 8 = 352 blocks
    mmv_kernel<<<grid, block, 0, stream>>>(x, pL, o);
}